// Round 6
// baseline (177.627 us; speedup 1.0000x reference)
//
#include <hip/hip_runtime.h>
#include <hip/hip_bf16.h>
#include <hip/hip_fp16.h>

// SumAggregator: out[n, :] = sum_{i<32} emb_table[neighs[n*32 + i], :], DIM=128.
// R6: XCD-sliced L2-resident gather.
//   phase 1: convert fp32 table -> fp16 in SLICED layout ws[s][id][16 dims]
//            (LDS transpose; slice region = 100K*32B = 3.2MB < 4MiB XCD L2).
//   phase 2: blocks with blockIdx%8==s gather only slice s (heuristic block->XCD
//            round-robin) -> gathers hit XCD-local L2 instead of the ~3.2TB/s
//            fabric path that capped R1/R3/R5. nt hints on streaming traffic
//            (indices, output, convert) keep the slice resident.

constexpr int DIM = 128;
constexpr int DIM4 = DIM / 4;     // float4 per row
constexpr int NB = 32;
constexpr int NSLICE = 8;
constexpr int SLICE_DIM = 16;     // dims per slice (32 B fp16 per id)

typedef float        floatx4 __attribute__((ext_vector_type(4)));
typedef unsigned int uintx4  __attribute__((ext_vector_type(4)));
typedef unsigned int uintx2  __attribute__((ext_vector_type(2)));
typedef int          intx4   __attribute__((ext_vector_type(4)));

// ---- phase 1: fp32 [id][128] -> fp16 sliced [s][id][16] via LDS transpose ----
__global__ __launch_bounds__(256) void convert_slice_kernel(
    const floatx4* __restrict__ emb,   // [num_ids][32] float4
    uintx4* __restrict__ ws,           // sliced fp16 table, 16B units
    int num_ids)
{
    __shared__ uintx2 lds[32][33];     // [id_local][chunk of 4 halves], +1 pad
    const int base = blockIdx.x * 32;
    const int t = threadIdx.x;

#pragma unroll
    for (int i = 0; i < 4; ++i) {
        int f = i * 256 + t;           // 0..1023 -> 32 rows x 32 float4-chunks
        int r = f >> 5, c = f & 31;
        if (base + r < num_ids) {
            floatx4 v = __builtin_nontemporal_load(&emb[(size_t)(base + r) * DIM4 + c]);
            __half2 h0 = __floats2half2_rn(v.x, v.y);
            __half2 h1 = __floats2half2_rn(v.z, v.w);
            uintx2 o;
            o.x = *reinterpret_cast<unsigned int*>(&h0);
            o.y = *reinterpret_cast<unsigned int*>(&h1);
            lds[r][c] = o;
        }
    }
    __syncthreads();

    const int s = t >> 5, r = t & 31;  // slice, id_local
    if (base + r < num_ids) {
        uintx2 a = lds[r][s * 4 + 0];
        uintx2 b = lds[r][s * 4 + 1];
        uintx2 c = lds[r][s * 4 + 2];
        uintx2 d = lds[r][s * 4 + 3];
        uintx4 w0 = {a.x, a.y, b.x, b.y};
        uintx4 w1 = {c.x, c.y, d.x, d.y};
        size_t o = ((size_t)s * num_ids + base + r) * 2;   // 32 B per id = 2 uintx4
        __builtin_nontemporal_store(w0, &ws[o]);
        __builtin_nontemporal_store(w1, &ws[o + 1]);
    }
}

// ---- phase 2: sliced gather; 2 lanes per node, fp32 accumulate ----
__global__ __launch_bounds__(256) void gather_slice_kernel(
    const int* __restrict__ neighs,
    const uintx4* __restrict__ ws,
    float* __restrict__ out,           // [node_count][128]
    int node_count, int num_ids)
{
    const int s     = blockIdx.x & 7;        // slice == target XCD (heuristic)
    const int chunk = blockIdx.x >> 3;       // 0..255
    const int t     = threadIdx.x;
    const int lane  = t & 63;
    const int half  = lane & 1;              // which 8-dim half of the slice
    const int pair  = lane >> 1;             // node within wave: 0..31
    const int wave  = t >> 6;                // 0..3

    const uintx4* slice = ws + (size_t)s * num_ids * 2;

    for (int node0 = chunk * 128; node0 < node_count; node0 += 256 * 128) {
        int node = node0 + wave * 32 + pair;
        if (node < node_count) {
            // my 16 of the node's 32 indices (other 16 live in partner lane)
            const intx4* ip = (const intx4*)(neighs + (size_t)node * NB + half * 16);
            intx4 i0 = __builtin_nontemporal_load(&ip[0]);
            intx4 i1 = __builtin_nontemporal_load(&ip[1]);
            intx4 i2 = __builtin_nontemporal_load(&ip[2]);
            intx4 i3 = __builtin_nontemporal_load(&ip[3]);
            int idx[16] = {i0.x, i0.y, i0.z, i0.w,  i1.x, i1.y, i1.z, i1.w,
                           i2.x, i2.y, i2.z, i2.w,  i3.x, i3.y, i3.z, i3.w};

            float acc[8] = {0.f, 0.f, 0.f, 0.f, 0.f, 0.f, 0.f, 0.f};
#pragma unroll
            for (int j = 0; j < NB; ++j) {
                int id = __shfl(idx[j & 15], j >> 4, 2);   // from my 2-lane pair
                uintx4 u = slice[(size_t)id * 2 + half];   // 16 B = 8 halves
                const __half2* hp = reinterpret_cast<const __half2*>(&u);
                float2 f;
                f = __half22float2(hp[0]); acc[0] += f.x; acc[1] += f.y;
                f = __half22float2(hp[1]); acc[2] += f.x; acc[3] += f.y;
                f = __half22float2(hp[2]); acc[4] += f.x; acc[5] += f.y;
                f = __half22float2(hp[3]); acc[6] += f.x; acc[7] += f.y;
            }

            floatx4 o0 = {acc[0], acc[1], acc[2], acc[3]};
            floatx4 o1 = {acc[4], acc[5], acc[6], acc[7]};
            float* op = out + (size_t)node * DIM + s * SLICE_DIM + half * 8;
            __builtin_nontemporal_store(o0, (floatx4*)op);
            __builtin_nontemporal_store(o1, (floatx4*)(op + 4));
        }
    }
}

// ---- fp32 fallback (ws too small or nb_count != 32) ----
__global__ __launch_bounds__(256) void gather_f32_kernel(
    const int* __restrict__ neighs,
    const float4* __restrict__ emb,
    float4* __restrict__ out,
    int node_count, int nb_count)
{
    int t = blockIdx.x * blockDim.x + threadIdx.x;
    int node = t >> 5;
    int lane = t & 31;
    if (node >= node_count) return;

    const int* __restrict__ idx = neighs + (size_t)node * nb_count;
    float4 acc = make_float4(0.f, 0.f, 0.f, 0.f);
    for (int i = 0; i < nb_count; ++i) {
        int id = idx[i];
        float4 v = emb[(size_t)id * DIM4 + lane];
        acc.x += v.x; acc.y += v.y; acc.z += v.z; acc.w += v.w;
    }
    out[(size_t)node * DIM4 + lane] = acc;
}

extern "C" void kernel_launch(void* const* d_in, const int* in_sizes, int n_in,
                              void* d_out, int out_size, void* d_ws, size_t ws_size,
                              hipStream_t stream)
{
    const int* neighs = (const int*)d_in[0];
    const float4* emb = (const float4*)d_in[2];

    const int node_count = out_size / DIM;             // 50000
    const int nb_count   = in_sizes[0] / node_count;   // 32
    const int num_ids    = in_sizes[2] / DIM;          // 100000

    const size_t ws_needed = (size_t)num_ids * DIM * sizeof(__half);  // 25.6 MB
    const int block = 256;

    if (nb_count == NB && ws_size >= ws_needed) {
        // phase 1: convert + transpose into sliced fp16 layout
        const int cgrid = (num_ids + 31) / 32;
        convert_slice_kernel<<<cgrid, block, 0, stream>>>(
            (const floatx4*)emb, (uintx4*)d_ws, num_ids);

        // phase 2: sliced gather; 2048 blocks = 8 slices x 256 chunks
        gather_slice_kernel<<<2048, block, 0, stream>>>(
            neighs, (const uintx4*)d_ws, (float*)d_out, node_count, num_ids);
    } else {
        const int threads_total = node_count * 32;
        const int grid = (threads_total + block - 1) / block;
        gather_f32_kernel<<<grid, block, 0, stream>>>(
            neighs, emb, (float4*)d_out, node_count, nb_count);
    }
}

// Round 7
// 159.186 us; speedup vs baseline: 1.1158x; 1.1158x over previous
//
#include <hip/hip_runtime.h>
#include <hip/hip_bf16.h>
#include <hip/hip_fp16.h>

// SumAggregator: out[n, :] = sum_{i<32} emb_table[neighs[n*32 + i], :], DIM=128.
// R7: sorted time-coherent gather.
//   convert: fp32 table -> fp16 [id][128] (exact grid, no stride imbalance)
//   prep:    per node, counting-sort its 32 indices by range (id>>13 = 2MB fp16
//            per range) via ballot; write sorted ids to ws.
//   gather:  all waves walk k=0..31 in lockstep over SORTED ids -> at step k the
//            whole machine touches ids near quantile k/32 => instantaneous table
//            window ~4-6MB ~ XCD L2 => gathers are L2 hits (R6 measured ~3cyc/line
//            for L2-local vs 5.3 fabric-random), while keeping R3's fully-used
//            coalesced 256B row loads (6.4M lines, the minimum at fp16).
//            8 nodes/wave => 8 independent row loads in flight; idx reads L1-hot.

constexpr int DIM = 128;
constexpr int NB = 32;
constexpr int SHIFT = 13;        // 8192 ids/range * 256B fp16 = 2MB per range

typedef float floatx4 __attribute__((ext_vector_type(4)));

// ---- phase 1: fp32 -> fp16, elementwise, exact grid ----
__global__ __launch_bounds__(256) void convert_kernel(
    const float4* __restrict__ emb,   // [num_ids*DIM/4]
    uint2* __restrict__ emb_h,        // [num_ids*DIM/4] (4 halves each)
    int n4)
{
    int i = blockIdx.x * blockDim.x + threadIdx.x;
    if (i >= n4) return;
    float4 v = emb[i];
    __half2 h0 = __floats2half2_rn(v.x, v.y);
    __half2 h1 = __floats2half2_rn(v.z, v.w);
    uint2 o;
    o.x = *reinterpret_cast<unsigned int*>(&h0);
    o.y = *reinterpret_cast<unsigned int*>(&h1);
    emb_h[i] = o;
}

// ---- phase 2: per-node counting sort of indices by range (ballot-based) ----
__global__ __launch_bounds__(256) void prep_kernel(
    const int* __restrict__ neighs,
    int* __restrict__ sorted,          // [node_count*NB]
    int node_count, int nr)
{
    const int t    = threadIdx.x;
    const int ln   = t & 31;           // lane within 32-group (one node/group)
    const int half = (t >> 5) & 1;     // which half of the wave64
    const int node = blockIdx.x * 8 + (t >> 5);
    if (node >= node_count) return;

    int my_idx = neighs[(size_t)node * NB + ln];
    int my_r   = my_idx >> SHIFT;

    const unsigned int below = (1u << ln) - 1u;
    int cum = 0, pos = 0;
    for (int r = 0; r < nr; ++r) {
        bool hit = (my_r == r);
        unsigned long long b = __ballot(hit);
        unsigned int gb = (unsigned int)(b >> (half * 32));
        if (hit) pos = cum + __popc(gb & below);
        cum += __popc(gb);
    }
    sorted[(size_t)node * NB + pos] = my_idx;
}

// ---- phase 3: lockstep sorted gather; 1 node per wave-row, 8 nodes per wave ----
__global__ __launch_bounds__(256) void gather_sorted(
    const unsigned int* __restrict__ tbl,   // fp16 table, [num_ids][64] uint
    const int* __restrict__ sorted,         // [node_count][NB]
    float2* __restrict__ out,               // [node_count][64]
    int node_count)
{
    const int lane  = threadIdx.x & 63;       // uint (2 halves) within the row
    const int wave  = threadIdx.x >> 6;
    const int node0 = blockIdx.x * 32 + wave * 8;

    // clamp node ids so dummy tail lanes do valid (redundant) loads
    int nc8[8];
#pragma unroll
    for (int ln = 0; ln < 8; ++ln) {
        int n = node0 + ln;
        nc8[ln] = (n < node_count) ? n : (node_count - 1);
    }

    float2 acc[8];
#pragma unroll
    for (int ln = 0; ln < 8; ++ln) acc[ln] = make_float2(0.f, 0.f);

    for (int k = 0; k < NB; ++k) {
        int id[8];
#pragma unroll
        for (int ln = 0; ln < 8; ++ln)
            id[ln] = sorted[(size_t)nc8[ln] * NB + k];   // L1-hot (1KB/wave)

        unsigned int u[8];
#pragma unroll
        for (int ln = 0; ln < 8; ++ln)
            u[ln] = tbl[(size_t)id[ln] * 64 + lane];     // 8 rows in flight

#pragma unroll
        for (int ln = 0; ln < 8; ++ln) {
            __half2 h = *reinterpret_cast<__half2*>(&u[ln]);
            float2 f = __half22float2(h);
            acc[ln].x += f.x;
            acc[ln].y += f.y;
        }
    }

#pragma unroll
    for (int ln = 0; ln < 8; ++ln) {
        int n = node0 + ln;
        if (n < node_count)
            out[(size_t)n * 64 + lane] = acc[ln];
    }
}

// ---- fp32 fallback (ws too small or nb_count != 32) ----
__global__ __launch_bounds__(256) void gather_f32_kernel(
    const int* __restrict__ neighs,
    const float4* __restrict__ emb,
    float4* __restrict__ out,
    int node_count, int nb_count)
{
    int t = blockIdx.x * blockDim.x + threadIdx.x;
    int node = t >> 5;
    int lane = t & 31;
    if (node >= node_count) return;

    const int* __restrict__ idx = neighs + (size_t)node * nb_count;
    float4 acc = make_float4(0.f, 0.f, 0.f, 0.f);
    for (int i = 0; i < nb_count; ++i) {
        int id = idx[i];
        float4 v = emb[(size_t)id * (DIM / 4) + lane];
        acc.x += v.x; acc.y += v.y; acc.z += v.z; acc.w += v.w;
    }
    out[(size_t)node * (DIM / 4) + lane] = acc;
}

extern "C" void kernel_launch(void* const* d_in, const int* in_sizes, int n_in,
                              void* d_out, int out_size, void* d_ws, size_t ws_size,
                              hipStream_t stream)
{
    const int* neighs = (const int*)d_in[0];
    const float4* emb = (const float4*)d_in[2];

    const int node_count = out_size / DIM;             // 50000
    const int nb_count   = in_sizes[0] / node_count;   // 32
    const int num_ids    = in_sizes[2] / DIM;          // 100000

    const size_t tbl_bytes = (size_t)num_ids * DIM * sizeof(__half);   // 25.6 MB
    const size_t ws_needed = tbl_bytes + (size_t)node_count * NB * 4;  // +6.4 MB

    const int block = 256;

    if (nb_count == NB && ws_size >= ws_needed) {
        unsigned int* tbl_h = (unsigned int*)d_ws;
        int* sorted = (int*)((char*)d_ws + tbl_bytes);
        const int nr = (num_ids + (1 << SHIFT) - 1) >> SHIFT;   // 13

        // phase 1: convert (exact grid, 1 uint2 per thread)
        const int n4 = num_ids * (DIM / 4);
        convert_kernel<<<(n4 + block - 1) / block, block, 0, stream>>>(
            emb, (uint2*)tbl_h, n4);

        // phase 2: per-node range sort (8 nodes per block)
        prep_kernel<<<(node_count + 7) / 8, block, 0, stream>>>(
            neighs, sorted, node_count, nr);

        // phase 3: lockstep sorted gather (32 nodes per block)
        gather_sorted<<<(node_count + 31) / 32, block, 0, stream>>>(
            tbl_h, sorted, (float2*)d_out, node_count);
    } else {
        const int threads_total = node_count * 32;
        const int grid = (threads_total + block - 1) / block;
        gather_f32_kernel<<<grid, block, 0, stream>>>(
            neighs, emb, (float4*)d_out, node_count, nb_count);
    }
}

// Round 8
// 154.016 us; speedup vs baseline: 1.1533x; 1.0336x over previous
//
#include <hip/hip_runtime.h>
#include <hip/hip_bf16.h>
#include <hip/hip_fp16.h>

// SumAggregator: out[n, :] = sum_{i<32} emb_table[neighs[n*32 + i], :], DIM=128.
// R8: R3's exact gather shape (best measured: 5.3 cyc/line) + R7's per-node
// range sort. ONLY delta vs R3: indices come pre-sorted -> lockstep walk gives
// temporal locality (R7 measured FETCH 174->136MB). Tests whether lower avg
// fill latency raises the MSHR-limited line rate (model: rate = ~32/latency).

constexpr int DIM = 128;
constexpr int DIM4 = DIM / 4;
constexpr int NB = 32;
constexpr int SHIFT = 13;        // 8192 ids/range * 256B fp16 = 2MB per range

// ---- phase 1: fp32 -> fp16, elementwise, exact grid ----
__global__ __launch_bounds__(256) void convert_kernel(
    const float4* __restrict__ emb,   // [num_ids*DIM/4]
    uint2* __restrict__ emb_h,        // [num_ids*DIM/4] (4 halves each)
    int n4)
{
    int i = blockIdx.x * blockDim.x + threadIdx.x;
    if (i >= n4) return;
    float4 v = emb[i];
    __half2 h0 = __floats2half2_rn(v.x, v.y);
    __half2 h1 = __floats2half2_rn(v.z, v.w);
    uint2 o;
    o.x = *reinterpret_cast<unsigned int*>(&h0);
    o.y = *reinterpret_cast<unsigned int*>(&h1);
    emb_h[i] = o;
}

// ---- phase 2: per-node counting sort of indices by range (ballot-based) ----
__global__ __launch_bounds__(256) void prep_kernel(
    const int* __restrict__ neighs,
    int* __restrict__ sorted,          // [node_count*NB]
    int node_count, int nr)
{
    const int t    = threadIdx.x;
    const int ln   = t & 31;           // lane within 32-group (one node/group)
    const int half = (t >> 5) & 1;     // which half of the wave64
    const int node = blockIdx.x * 8 + (t >> 5);
    if (node >= node_count) return;

    int my_idx = neighs[(size_t)node * NB + ln];
    int my_r   = my_idx >> SHIFT;

    const unsigned int below = (1u << ln) - 1u;
    int cum = 0, pos = 0;
    for (int r = 0; r < nr; ++r) {
        bool hit = (my_r == r);
        unsigned long long b = __ballot(hit);
        unsigned int gb = (unsigned int)(b >> (half * 32));
        if (hit) pos = cum + __popc(gb & below);
        cum += __popc(gb);
    }
    sorted[(size_t)node * NB + pos] = my_idx;
}

// ---- phase 3: R3-shape gather over sorted indices ----
__global__ __launch_bounds__(256) void gather_h_kernel(
    const int* __restrict__ sorted,
    const uint2* __restrict__ emb_h,  // [num_ids][DIM4] 8B chunks
    float4* __restrict__ out,         // [node_count][DIM4]
    int node_count)
{
    int t = blockIdx.x * blockDim.x + threadIdx.x;
    int node = t >> 5;
    int lane = t & 31;
    if (node >= node_count) return;

    int my_idx = sorted[node * NB + lane];   // coalesced 128B per 32-group

    float4 acc = make_float4(0.f, 0.f, 0.f, 0.f);
#pragma unroll 8
    for (int i = 0; i < NB; ++i) {
        int id = __shfl(my_idx, i, 32);      // ascending id order across k
        uint2 u = emb_h[(size_t)id * DIM4 + lane];   // 8B/lane, 256B/row
        __half2 p0 = *reinterpret_cast<__half2*>(&u.x);
        __half2 p1 = *reinterpret_cast<__half2*>(&u.y);
        float2 f0 = __half22float2(p0);
        float2 f1 = __half22float2(p1);
        acc.x += f0.x; acc.y += f0.y; acc.z += f1.x; acc.w += f1.y;
    }
    out[(size_t)node * DIM4 + lane] = acc;
}

// ---- fp32 fallback (ws too small or nb_count != 32) ----
__global__ __launch_bounds__(256) void gather_f32_kernel(
    const int* __restrict__ neighs,
    const float4* __restrict__ emb,
    float4* __restrict__ out,
    int node_count, int nb_count)
{
    int t = blockIdx.x * blockDim.x + threadIdx.x;
    int node = t >> 5;
    int lane = t & 31;
    if (node >= node_count) return;

    const int* __restrict__ idx = neighs + (size_t)node * nb_count;
    float4 acc = make_float4(0.f, 0.f, 0.f, 0.f);
    for (int i = 0; i < nb_count; ++i) {
        int id = idx[i];
        float4 v = emb[(size_t)id * DIM4 + lane];
        acc.x += v.x; acc.y += v.y; acc.z += v.z; acc.w += v.w;
    }
    out[(size_t)node * DIM4 + lane] = acc;
}

extern "C" void kernel_launch(void* const* d_in, const int* in_sizes, int n_in,
                              void* d_out, int out_size, void* d_ws, size_t ws_size,
                              hipStream_t stream)
{
    const int* neighs = (const int*)d_in[0];
    const float4* emb = (const float4*)d_in[2];

    const int node_count = out_size / DIM;             // 50000
    const int nb_count   = in_sizes[0] / node_count;   // 32
    const int num_ids    = in_sizes[2] / DIM;          // 100000

    const size_t tbl_bytes = (size_t)num_ids * DIM * sizeof(__half);   // 25.6 MB
    const size_t ws_needed = tbl_bytes + (size_t)node_count * NB * 4;  // +6.4 MB

    const int block = 256;

    if (nb_count == NB && ws_size >= ws_needed) {
        uint2* tbl_h = (uint2*)d_ws;
        int* sorted = (int*)((char*)d_ws + tbl_bytes);
        const int nr = (num_ids + (1 << SHIFT) - 1) >> SHIFT;   // 13

        // phase 1: convert (exact grid, 1 uint2 per thread)
        const int n4 = num_ids * DIM4;
        convert_kernel<<<(n4 + block - 1) / block, block, 0, stream>>>(
            emb, tbl_h, n4);

        // phase 2: per-node range sort (8 nodes per block)
        prep_kernel<<<(node_count + 7) / 8, block, 0, stream>>>(
            neighs, sorted, node_count, nr);

        // phase 3: R3-shape gather over sorted ids
        const int threads_total = node_count * 32;
        gather_h_kernel<<<(threads_total + block - 1) / block, block, 0, stream>>>(
            sorted, tbl_h, (float4*)d_out, node_count);
    } else {
        const int threads_total = node_count * 32;
        const int grid = (threads_total + block - 1) / block;
        gather_f32_kernel<<<grid, block, 0, stream>>>(
            neighs, emb, (float4*)d_out, node_count, nb_count);
    }
}